// Round 5
// baseline (130.323 us; speedup 1.0000x reference)
//
#include <hip/hip_runtime.h>

typedef __attribute__((ext_vector_type(8))) __bf16 bf16x8;
typedef __attribute__((ext_vector_type(8))) unsigned short u16x8;
typedef __attribute__((ext_vector_type(4))) unsigned short u16x4;
typedef __attribute__((ext_vector_type(4))) float f32x4;

__device__ __forceinline__ f32x4 mfma16(bf16x8 a, bf16x8 b, f32x4 c) {
  return __builtin_amdgcn_mfma_f32_16x16x32_bf16(a, b, c, 0, 0, 0);
}

__device__ __forceinline__ bf16x8 cvt8(f32x4 a, f32x4 b) {
  bf16x8 r;
  r[0] = (__bf16)a[0]; r[1] = (__bf16)a[1]; r[2] = (__bf16)a[2]; r[3] = (__bf16)a[3];
  r[4] = (__bf16)b[0]; r[5] = (__bf16)b[1]; r[6] = (__bf16)b[2]; r[7] = (__bf16)b[3];
  return r;
}

__device__ __forceinline__ unsigned short bf1(float f) {
  return __builtin_bit_cast(unsigned short, (__bf16)f);
}

__device__ __forceinline__ bf16x8 ld_frag(const unsigned short* p) {
  return __builtin_bit_cast(bf16x8, *(const u16x8*)p);
}

// ---------------------------------------------------------------------------
// kprep: blocks 0..31 -> BwF frags, 32..63 -> CwF frags, block 64 -> A powers
// (akbF frags), sigma_max(A), dflag, norm_out=0.  (unchanged from R3/R4)
// ---------------------------------------------------------------------------
__global__ __launch_bounds__(256) void kprep(const float* __restrict__ Bw,
                                             const float* __restrict__ Cw,
                                             const float* __restrict__ Al,
                                             const float* __restrict__ Ah,
                                             const float* __restrict__ Dv,
                                             unsigned short* __restrict__ BwF,
                                             unsigned short* __restrict__ CwF,
                                             unsigned short* __restrict__ akbF,
                                             float* __restrict__ dflag,
                                             float* __restrict__ spec,
                                             float* __restrict__ norm_out) {
  const int bid = blockIdx.x, tid = threadIdx.x;
  if (bid < 32) {
    int g = bid * 256 + tid;
    int kstep = g >> 8, nt = (g >> 6) & 3, ln = g & 63;
    int n = nt * 16 + (ln & 15);
    int k = kstep * 32 + (ln >> 4) * 8;
    f32x4 a = *(const f32x4*)&Bw[(size_t)n * 1024 + k];
    f32x4 b = *(const f32x4*)&Bw[(size_t)n * 1024 + k + 4];
    *(u16x8*)&BwF[(size_t)g * 8] = __builtin_bit_cast(u16x8, cvt8(a, b));
    return;
  }
  if (bid < 64) {
    int g = (bid - 32) * 256 + tid;
    int dt = g >> 7, kk = (g >> 6) & 1, ln = g & 63;
    int d = dt * 16 + (ln & 15);
    int n = kk * 32 + (ln >> 4) * 8;
    f32x4 a = *(const f32x4*)&Cw[(size_t)d * 64 + n];
    f32x4 b = *(const f32x4*)&Cw[(size_t)d * 64 + n + 4];
    *(u16x8*)&CwF[(size_t)g * 8] = __builtin_bit_cast(u16x8, cvt8(a, b));
    return;
  }
  __shared__ float A[4][64][68];
  __shared__ float Alo[64][36];
  __shared__ float Ahi[32][68];
  const int lane = tid & 63, wq = tid >> 6;
  for (int f = tid; f < 512; f += 256) {
    int r = f >> 3, c = (f & 7) << 2;
    *(f32x4*)&Alo[r][c] = *(const f32x4*)&Al[r * 32 + c];
  }
  for (int f = tid; f < 512; f += 256) {
    int r = f >> 4, c = (f & 15) << 2;
    *(f32x4*)&Ahi[r][c] = *(const f32x4*)&Ah[r * 64 + c];
  }
  if (tid == 0) *norm_out = 0.0f;
  __syncthreads();
  {
    float ar[32];
#pragma unroll
    for (int r = 0; r < 32; r++) ar[r] = Alo[lane][r];
#pragma unroll
    for (int m4 = 0; m4 < 4; m4++) {
      f32x4 s = {0.f, 0.f, 0.f, 0.f};
#pragma unroll
      for (int r = 0; r < 32; r++)
        s += ar[r] * *(const f32x4*)&Ahi[r][wq * 16 + m4 * 4];
      *(f32x4*)&A[0][lane][wq * 16 + m4 * 4] = s;
    }
  }
  __syncthreads();
  for (int p = 1; p < 4; p++) {
    float ar[64];
#pragma unroll
    for (int k = 0; k < 64; k++) ar[k] = A[p - 1][lane][k];
#pragma unroll
    for (int m4 = 0; m4 < 4; m4++) {
      f32x4 s = {0.f, 0.f, 0.f, 0.f};
#pragma unroll
      for (int k = 0; k < 64; k++)
        s += ar[k] * *(const f32x4*)&A[0][k][wq * 16 + m4 * 4];
      *(f32x4*)&A[p][lane][wq * 16 + m4 * 4] = s;
    }
    __syncthreads();
  }
#pragma unroll
  for (int i = 0; i < 8; i++) {
    int e = tid + 256 * i;
    int kp = e >> 9, kk = (e >> 8) & 1, nt = (e >> 6) & 3, ln = e & 63;
    int n = nt * 16 + (ln & 15);
    int mc = kk * 32 + (ln >> 4) * 8;
    f32x4 a = *(const f32x4*)&A[kp][n][mc];
    f32x4 b = *(const f32x4*)&A[kp][n][mc + 4];
    *(u16x8*)&akbF[(size_t)e * 8] = __builtin_bit_cast(u16x8, cvt8(a, b));
  }
  if (wq == 0) {
    float ar[64], at[64];
#pragma unroll
    for (int m = 0; m < 64; m++) { ar[m] = A[0][lane][m]; at[m] = A[0][m][lane]; }
    float v = 1.0f + 0.001f * (float)lane;
    for (int it = 0; it < 8; it++) {
      float w = 0.f;
#pragma unroll
      for (int m = 0; m < 64; m++) w += ar[m] * __shfl(v, m, 64);
      float z = 0.f;
#pragma unroll
      for (int m = 0; m < 64; m++) z += at[m] * __shfl(w, m, 64);
      float ss = z * z;
#pragma unroll
      for (int off = 32; off; off >>= 1) ss += __shfl_xor(ss, off, 64);
      v = z * rsqrtf(ss + 1e-38f);
    }
    float w = 0.f;
#pragma unroll
    for (int m = 0; m < 64; m++) w += ar[m] * __shfl(v, m, 64);
    float ss = w * w;
#pragma unroll
    for (int off = 32; off; off >>= 1) ss += __shfl_xor(ss, off, 64);
    if (lane == 0) *spec = sqrtf(ss);
  }
  if (wq == 1) {
    float dm = 0.f;
#pragma unroll
    for (int i = 0; i < 16; i++) dm = fmaxf(dm, fabsf(Dv[lane + i * 64]));
#pragma unroll
    for (int off = 32; off; off >>= 1) dm = fmaxf(dm, __shfl_xor(dm, off, 64));
    if (lane == 0) *dflag = dm;
  }
}

// ---------------------------------------------------------------------------
// MONO: per 4-wave block, 64 t-rows end-to-end.
// Phase A: wave w computes u-tile rows t0+16w..+15 (MFMA vs BwF) -> registers
//          + LDS uL; wave 0 also computes the 4-row halo tile (rows t0-4..-1,
//          only those 4 x rows loaded). One __syncthreads.
// Phase B: k2 from uL (identity term from phase-A registers), state-norm
//          atomic, per-wave hsT transpose, g2 dc-loop (CwF frags) + stores.
// ---------------------------------------------------------------------------
__global__ __launch_bounds__(256) void mono(const float* __restrict__ x,
                                            const unsigned short* __restrict__ BwF,
                                            const float* __restrict__ Bb,
                                            const float* __restrict__ rw,
                                            const unsigned short* __restrict__ akbF,
                                            const unsigned short* __restrict__ CwF,
                                            const float* __restrict__ Cb,
                                            const float* __restrict__ Dv,
                                            const float* __restrict__ dflag,
                                            float* __restrict__ out,
                                            float* __restrict__ norm_out) {
  __shared__ float uL[68][68];                 // rows 0..3 = halo t0-4..t0-1
  __shared__ unsigned short hsT[4][16][72];
  const int tid = threadIdx.x, lane = tid & 63, wid = tid >> 6;
  const int t0 = blockIdx.x * 64;
  const int l15 = lane & 15;
  const int q8 = (lane >> 4) * 8;
  const int n4 = (lane >> 4) * 4;
  const bool hasD = (*dflag != 0.0f);

  // ---------------- Phase A ----------------
  const int trowA = t0 + wid * 16 + l15;
  f32x4 acc[4];
#pragma unroll
  for (int nt = 0; nt < 4; nt++) acc[nt] = f32x4{0.f, 0.f, 0.f, 0.f};

  if (wid == 0) {
    const int trowH = t0 - 16 + l15;           // only l15>=12 rows are real
    const bool hload = (l15 >= 12) && (trowH >= 0);
    const float* hp0 = &x[(size_t)(hload ? trowH : 0) * 1024];
    f32x4 accH[4];
#pragma unroll
    for (int nt = 0; nt < 4; nt++) accH[nt] = f32x4{0.f, 0.f, 0.f, 0.f};
#pragma unroll 4
    for (int ks = 0; ks < 32; ks++) {
      const float* xp = &x[(size_t)trowA * 1024 + ks * 32 + q8];
      bf16x8 bm = cvt8(*(const f32x4*)xp, *(const f32x4*)(xp + 4));
      f32x4 ha = {0.f, 0.f, 0.f, 0.f}, hb = {0.f, 0.f, 0.f, 0.f};
      if (hload) {
        ha = *(const f32x4*)(hp0 + ks * 32 + q8);
        hb = *(const f32x4*)(hp0 + ks * 32 + q8 + 4);
      }
      bf16x8 bh = cvt8(ha, hb);
#pragma unroll
      for (int nt = 0; nt < 4; nt++) {
        bf16x8 a = ld_frag(&BwF[((size_t)(ks * 4 + nt) * 64 + lane) * 8]);
        acc[nt] = mfma16(a, bm, acc[nt]);
        accH[nt] = mfma16(a, bh, accH[nt]);
      }
    }
    const float rwh = rw[trowH < 0 ? 0 : trowH];
#pragma unroll
    for (int nt = 0; nt < 4; nt++) {
      f32x4 bb = *(const f32x4*)&Bb[nt * 16 + n4];
      f32x4 o;
#pragma unroll
      for (int j = 0; j < 4; j++) o[j] = (accH[nt][j] + bb[j]) * rwh;
      if (l15 >= 12) *(f32x4*)&uL[l15 - 12][nt * 16 + n4] = o;
    }
  } else {
#pragma unroll 8
    for (int ks = 0; ks < 32; ks++) {
      const float* xp = &x[(size_t)trowA * 1024 + ks * 32 + q8];
      bf16x8 bm = cvt8(*(const f32x4*)xp, *(const f32x4*)(xp + 4));
#pragma unroll
      for (int nt = 0; nt < 4; nt++) {
        bf16x8 a = ld_frag(&BwF[((size_t)(ks * 4 + nt) * 64 + lane) * 8]);
        acc[nt] = mfma16(a, bm, acc[nt]);
      }
    }
  }
  const float rwt = rw[trowA];
  f32x4 ureg[4];
#pragma unroll
  for (int nt = 0; nt < 4; nt++) {
    f32x4 bb = *(const f32x4*)&Bb[nt * 16 + n4];
#pragma unroll
    for (int j = 0; j < 4; j++) ureg[nt][j] = (acc[nt][j] + bb[j]) * rwt;
    *(f32x4*)&uL[4 + wid * 16 + l15][nt * 16 + n4] = ureg[nt];
  }
  __syncthreads();

  // ---------------- Phase B: k2 ----------------
  const int orow = trowA;                       // output row this lane's col
  const int bst = orow & ~4095;
  f32x4 h[4];
#pragma unroll
  for (int nt = 0; nt < 4; nt++) h[nt] = f32x4{0.f, 0.f, 0.f, 0.f};
#pragma unroll
  for (int kp = 1; kp <= 4; kp++) {
    const bool ok = (orow - kp) >= bst;
    const int idx = wid * 16 + l15 - kp + 4;
    f32x4 xa = {0.f, 0.f, 0.f, 0.f}, xb = xa, ya = xa, yb = xa;
    if (ok) {
      xa = *(const f32x4*)&uL[idx][q8];
      xb = *(const f32x4*)&uL[idx][q8 + 4];
      ya = *(const f32x4*)&uL[idx][32 + q8];
      yb = *(const f32x4*)&uL[idx][32 + q8 + 4];
    }
    bf16x8 b0 = cvt8(xa, xb);
    bf16x8 b1 = cvt8(ya, yb);
#pragma unroll
    for (int nt = 0; nt < 4; nt++) {
      bf16x8 a0 = ld_frag(&akbF[(size_t)((((kp - 1) * 2 + 0) * 4 + nt) * 64 + lane) * 8]);
      bf16x8 a1 = ld_frag(&akbF[(size_t)((((kp - 1) * 2 + 1) * 4 + nt) * 64 + lane) * 8]);
      h[nt] = mfma16(a0, b0, h[nt]);
      h[nt] = mfma16(a1, b1, h[nt]);
    }
  }
#pragma unroll
  for (int nt = 0; nt < 4; nt++) h[nt] += ureg[nt];   // identity term, f32

  // state norm (batch-end rows live at l15==15 of the right wave)
  const bool bend = ((t0 + wid * 16 + 15) & 4095) == 4095;
  if (bend) {
    float ss = 0.f;
    if (l15 == 15) {
#pragma unroll
      for (int nt = 0; nt < 4; nt++)
#pragma unroll
        for (int j = 0; j < 4; j++) ss += h[nt][j] * h[nt][j];
    }
    ss += __shfl_xor(ss, 16, 64);
    ss += __shfl_xor(ss, 32, 64);
    if (lane == 15) atomicAdd(norm_out, sqrtf(ss) * 0.125f);
  }

  // per-wave transpose: hs -> B-frag layout (col=t, k=n)
#pragma unroll
  for (int nt = 0; nt < 4; nt++) {
    u16x4 pk;
#pragma unroll
    for (int j = 0; j < 4; j++) pk[j] = bf1(h[nt][j]);
    *(u16x4*)&hsT[wid][l15][nt * 16 + n4] = pk;
  }
  bf16x8 hf[2];
#pragma unroll
  for (int kk = 0; kk < 2; kk++)
    hf[kk] = ld_frag(&hsT[wid][l15][kk * 32 + q8]);

  // ---------------- Phase B: g2 ----------------
  const size_t xrow = (size_t)orow * 1024;
#pragma unroll 4
  for (int dc = 0; dc < 16; dc++) {
    const int d0 = dc * 64;
    f32x4 o[4];
#pragma unroll
    for (int dt = 0; dt < 4; dt++) o[dt] = f32x4{0.f, 0.f, 0.f, 0.f};
#pragma unroll
    for (int kk = 0; kk < 2; kk++)
#pragma unroll
      for (int dt = 0; dt < 4; dt++) {
        bf16x8 a = ld_frag(&CwF[(size_t)((((d0 >> 4) + dt) * 2 + kk) * 64 + lane) * 8]);
        o[dt] = mfma16(a, hf[kk], o[dt]);
      }
#pragma unroll
    for (int dt = 0; dt < 4; dt++) {
      int db = d0 + dt * 16 + n4;
      f32x4 cb = *(const f32x4*)&Cb[db];
      f32x4 v = o[dt] + cb;
      if (hasD) {
        f32x4 dd = *(const f32x4*)&Dv[db];
        f32x4 xv = *(const f32x4*)&x[xrow + db];
        v += dd * xv;
      }
      *(f32x4*)&out[xrow + db] = v;
    }
  }
}

extern "C" void kernel_launch(void* const* d_in, const int* in_sizes, int n_in,
                              void* d_out, int out_size, void* d_ws, size_t ws_size,
                              hipStream_t stream) {
  const float* x  = (const float*)d_in[0];
  const float* rw = (const float*)d_in[1];
  const float* Al = (const float*)d_in[2];
  const float* Ah = (const float*)d_in[3];
  const float* Bw = (const float*)d_in[4];
  const float* Bb = (const float*)d_in[5];
  const float* Cw = (const float*)d_in[6];
  const float* Cb = (const float*)d_in[7];
  const float* Dv = (const float*)d_in[8];
  float* out = (float*)d_out;

  char* ws = (char*)d_ws;
  unsigned short* akbF  = (unsigned short*)(ws);            // 32 KiB
  float*          dflag = (float*)(ws + 32768);             // 4 B
  unsigned short* BwF   = (unsigned short*)(ws + 65536);    // 128 KiB
  unsigned short* CwF   = (unsigned short*)(ws + 196608);   // 128 KiB

  float* norm_out = out + (out_size - 2);
  float* spec_out = out + (out_size - 1);

  kprep<<<dim3(65), dim3(256), 0, stream>>>(Bw, Cw, Al, Ah, Dv, BwF, CwF, akbF,
                                            dflag, spec_out, norm_out);
  mono<<<dim3(512), dim3(256), 0, stream>>>(x, BwF, Bb, rw, akbF, CwF, Cb, Dv,
                                            dflag, out, norm_out);
}

// Round 6
// 112.262 us; speedup vs baseline: 1.1609x; 1.1609x over previous
//
#include <hip/hip_runtime.h>

typedef __attribute__((ext_vector_type(8))) __bf16 bf16x8;
typedef __attribute__((ext_vector_type(8))) unsigned short u16x8;
typedef __attribute__((ext_vector_type(4))) unsigned short u16x4;
typedef __attribute__((ext_vector_type(4))) float f32x4;

__device__ __forceinline__ f32x4 mfma16(bf16x8 a, bf16x8 b, f32x4 c) {
  return __builtin_amdgcn_mfma_f32_16x16x32_bf16(a, b, c, 0, 0, 0);
}

__device__ __forceinline__ bf16x8 cvt8(f32x4 a, f32x4 b) {
  bf16x8 r;
  r[0] = (__bf16)a[0]; r[1] = (__bf16)a[1]; r[2] = (__bf16)a[2]; r[3] = (__bf16)a[3];
  r[4] = (__bf16)b[0]; r[5] = (__bf16)b[1]; r[6] = (__bf16)b[2]; r[7] = (__bf16)b[3];
  return r;
}

__device__ __forceinline__ unsigned short bf1(float f) {
  return __builtin_bit_cast(unsigned short, (__bf16)f);
}

__device__ __forceinline__ bf16x8 ld_frag(const unsigned short* p) {
  return __builtin_bit_cast(bf16x8, *(const u16x8*)p);
}

// ---------------------------------------------------------------------------
// kprep: blocks 0..31 -> BwF frags, 32..63 -> CwF frags, block 64 -> A powers
// (akbF frags), sigma_max(A), dflag, norm_out=0.
// ---------------------------------------------------------------------------
__global__ __launch_bounds__(256) void kprep(const float* __restrict__ Bw,
                                             const float* __restrict__ Cw,
                                             const float* __restrict__ Al,
                                             const float* __restrict__ Ah,
                                             const float* __restrict__ Dv,
                                             unsigned short* __restrict__ BwF,
                                             unsigned short* __restrict__ CwF,
                                             unsigned short* __restrict__ akbF,
                                             float* __restrict__ dflag,
                                             float* __restrict__ spec,
                                             float* __restrict__ norm_out) {
  const int bid = blockIdx.x, tid = threadIdx.x;
  if (bid < 32) {
    int g = bid * 256 + tid;
    int kstep = g >> 8, nt = (g >> 6) & 3, ln = g & 63;
    int n = nt * 16 + (ln & 15);
    int k = kstep * 32 + (ln >> 4) * 8;
    f32x4 a = *(const f32x4*)&Bw[(size_t)n * 1024 + k];
    f32x4 b = *(const f32x4*)&Bw[(size_t)n * 1024 + k + 4];
    *(u16x8*)&BwF[(size_t)g * 8] = __builtin_bit_cast(u16x8, cvt8(a, b));
    return;
  }
  if (bid < 64) {
    int g = (bid - 32) * 256 + tid;
    int dt = g >> 7, kk = (g >> 6) & 1, ln = g & 63;
    int d = dt * 16 + (ln & 15);
    int n = kk * 32 + (ln >> 4) * 8;
    f32x4 a = *(const f32x4*)&Cw[(size_t)d * 64 + n];
    f32x4 b = *(const f32x4*)&Cw[(size_t)d * 64 + n + 4];
    *(u16x8*)&CwF[(size_t)g * 8] = __builtin_bit_cast(u16x8, cvt8(a, b));
    return;
  }
  __shared__ float A[4][64][68];
  __shared__ float Alo[64][36];
  __shared__ float Ahi[32][68];
  const int lane = tid & 63, wq = tid >> 6;
  for (int f = tid; f < 512; f += 256) {
    int r = f >> 3, c = (f & 7) << 2;
    *(f32x4*)&Alo[r][c] = *(const f32x4*)&Al[r * 32 + c];
  }
  for (int f = tid; f < 512; f += 256) {
    int r = f >> 4, c = (f & 15) << 2;
    *(f32x4*)&Ahi[r][c] = *(const f32x4*)&Ah[r * 64 + c];
  }
  if (tid == 0) *norm_out = 0.0f;
  __syncthreads();
  {
    float ar[32];
#pragma unroll
    for (int r = 0; r < 32; r++) ar[r] = Alo[lane][r];
#pragma unroll
    for (int m4 = 0; m4 < 4; m4++) {
      f32x4 s = {0.f, 0.f, 0.f, 0.f};
#pragma unroll
      for (int r = 0; r < 32; r++)
        s += ar[r] * *(const f32x4*)&Ahi[r][wq * 16 + m4 * 4];
      *(f32x4*)&A[0][lane][wq * 16 + m4 * 4] = s;
    }
  }
  __syncthreads();
  for (int p = 1; p < 4; p++) {
    float ar[64];
#pragma unroll
    for (int k = 0; k < 64; k++) ar[k] = A[p - 1][lane][k];
#pragma unroll
    for (int m4 = 0; m4 < 4; m4++) {
      f32x4 s = {0.f, 0.f, 0.f, 0.f};
#pragma unroll
      for (int k = 0; k < 64; k++)
        s += ar[k] * *(const f32x4*)&A[0][k][wq * 16 + m4 * 4];
      *(f32x4*)&A[p][lane][wq * 16 + m4 * 4] = s;
    }
    __syncthreads();
  }
#pragma unroll
  for (int i = 0; i < 8; i++) {
    int e = tid + 256 * i;
    int kp = e >> 9, kk = (e >> 8) & 1, nt = (e >> 6) & 3, ln = e & 63;
    int n = nt * 16 + (ln & 15);
    int mc = kk * 32 + (ln >> 4) * 8;
    f32x4 a = *(const f32x4*)&A[kp][n][mc];
    f32x4 b = *(const f32x4*)&A[kp][n][mc + 4];
    *(u16x8*)&akbF[(size_t)e * 8] = __builtin_bit_cast(u16x8, cvt8(a, b));
  }
  if (wq == 0) {
    float ar[64], at[64];
#pragma unroll
    for (int m = 0; m < 64; m++) { ar[m] = A[0][lane][m]; at[m] = A[0][m][lane]; }
    float v = 1.0f + 0.001f * (float)lane;
    for (int it = 0; it < 8; it++) {
      float w = 0.f;
#pragma unroll
      for (int m = 0; m < 64; m++) w += ar[m] * __shfl(v, m, 64);
      float z = 0.f;
#pragma unroll
      for (int m = 0; m < 64; m++) z += at[m] * __shfl(w, m, 64);
      float ss = z * z;
#pragma unroll
      for (int off = 32; off; off >>= 1) ss += __shfl_xor(ss, off, 64);
      v = z * rsqrtf(ss + 1e-38f);
    }
    float w = 0.f;
#pragma unroll
    for (int m = 0; m < 64; m++) w += ar[m] * __shfl(v, m, 64);
    float ss = w * w;
#pragma unroll
    for (int off = 32; off; off >>= 1) ss += __shfl_xor(ss, off, 64);
    if (lane == 0) *spec = sqrtf(ss);
  }
  if (wq == 1) {
    float dm = 0.f;
#pragma unroll
    for (int i = 0; i < 16; i++) dm = fmaxf(dm, fabsf(Dv[lane + i * 64]));
#pragma unroll
    for (int off = 32; off; off >>= 1) dm = fmaxf(dm, __shfl_xor(dm, off, 64));
    if (lane == 0) *dflag = dm;
  }
}

// ---------------------------------------------------------------------------
// G1 (split-K x2, software-pipelined): u[t][n] = (x·Bw^T + Bb)[t][n] * rw[t]
// 8 waves/block: rt = wid&3 (four 16-row tiles), kh = wid>>2 (K half).
// Next-iteration x + B-frag loads issued BEFORE current MFMAs.
// ---------------------------------------------------------------------------
__global__ __launch_bounds__(512, 4) void g1_gemm(const float* __restrict__ x,
                                                  const unsigned short* __restrict__ BwF,
                                                  const float* __restrict__ Bb,
                                                  const float* __restrict__ rw,
                                                  float* __restrict__ u) {
  __shared__ f32x4 accS[4][4][64];
  const int tid = threadIdx.x, lane = tid & 63, wid = tid >> 6;
  const int rt = wid & 3, kh = wid >> 2;
  const int t0 = blockIdx.x * 64 + rt * 16;
  const int trow = t0 + (lane & 15);
  const int q8 = (lane >> 4) * 8;
  const float* xrow = &x[(size_t)trow * 1024 + kh * 512 + q8];
  f32x4 acc[4];
#pragma unroll
  for (int nt = 0; nt < 4; nt++) acc[nt] = f32x4{0.f, 0.f, 0.f, 0.f};
  const int ksb = kh * 16;
  f32x4 pxa = *(const f32x4*)(xrow);
  f32x4 pxb = *(const f32x4*)(xrow + 4);
  bf16x8 pb[4];
#pragma unroll
  for (int nt = 0; nt < 4; nt++)
    pb[nt] = ld_frag(&BwF[((size_t)(ksb * 4 + nt) * 64 + lane) * 8]);
#pragma unroll
  for (int i = 0; i < 16; i++) {
    f32x4 cxa = pxa, cxb = pxb;
    bf16x8 cb0 = pb[0], cb1 = pb[1], cb2 = pb[2], cb3 = pb[3];
    if (i < 15) {
      pxa = *(const f32x4*)(xrow + (i + 1) * 32);
      pxb = *(const f32x4*)(xrow + (i + 1) * 32 + 4);
#pragma unroll
      for (int nt = 0; nt < 4; nt++)
        pb[nt] = ld_frag(&BwF[((size_t)((ksb + i + 1) * 4 + nt) * 64 + lane) * 8]);
    }
    bf16x8 bop = cvt8(cxa, cxb);
    acc[0] = mfma16(cb0, bop, acc[0]);
    acc[1] = mfma16(cb1, bop, acc[1]);
    acc[2] = mfma16(cb2, bop, acc[2]);
    acc[3] = mfma16(cb3, bop, acc[3]);
  }
  if (kh == 1) {
#pragma unroll
    for (int nt = 0; nt < 4; nt++) accS[rt][nt][lane] = acc[nt];
  }
  __syncthreads();
  if (kh == 0) {
    const float rwt = rw[trow];
#pragma unroll
    for (int nt = 0; nt < 4; nt++) {
      acc[nt] += accS[rt][nt][lane];
      int n0 = nt * 16 + (lane >> 4) * 4;
      f32x4 bb = *(const f32x4*)&Bb[n0];
      f32x4 o;
#pragma unroll
      for (int j = 0; j < 4; j++) o[j] = (acc[nt][j] + bb[j]) * rwt;
      *(f32x4*)&u[(size_t)trow * 64 + n0] = o;
    }
  }
}

// ---------------------------------------------------------------------------
// K2: hs = u + sum_{kp=1..4} A^kp u_{t-kp}; writes hs straight in B-frag
// layout (hsbF) via per-wave LDS transpose; state-norm atomic.
// One wave per 16-row t-tile, 2048 waves.
// ---------------------------------------------------------------------------
__global__ __launch_bounds__(256) void k2_hs(const float* __restrict__ u,
                                             const unsigned short* __restrict__ akbF,
                                             unsigned short* __restrict__ hsbF,
                                             float* __restrict__ norm_out) {
  __shared__ unsigned short hsT[4][16][72];
  const int tid = threadIdx.x, lane = tid & 63, wid = tid >> 6;
  const int tt = blockIdx.x * 4 + wid;
  const int t0 = tt * 16;
  const int bst = t0 & ~4095;
  const int l15 = lane & 15;
  const int q8 = (lane >> 4) * 8;
  const int n4 = (lane >> 4) * 4;
  const int tcol = t0 + l15;
  f32x4 h[4];
#pragma unroll
  for (int nt = 0; nt < 4; nt++) h[nt] = f32x4{0.f, 0.f, 0.f, 0.f};
#pragma unroll
  for (int kp = 1; kp <= 4; kp++) {
    const bool ok = (tcol - kp) >= bst;
    const float* up = &u[(size_t)(tcol - kp) * 64];
#pragma unroll
    for (int kk = 0; kk < 2; kk++) {
      f32x4 xa = {0.f, 0.f, 0.f, 0.f}, xb = {0.f, 0.f, 0.f, 0.f};
      if (ok) {
        xa = *(const f32x4*)(up + kk * 32 + q8);
        xb = *(const f32x4*)(up + kk * 32 + q8 + 4);
      }
      bf16x8 b = cvt8(xa, xb);
#pragma unroll
      for (int nt = 0; nt < 4; nt++) {
        bf16x8 a = ld_frag(&akbF[(size_t)((((kp - 1) * 2 + kk) * 4 + nt) * 64 + lane) * 8]);
        h[nt] = mfma16(a, b, h[nt]);
      }
    }
  }
#pragma unroll
  for (int nt = 0; nt < 4; nt++) {
    f32x4 uid = *(const f32x4*)&u[(size_t)tcol * 64 + nt * 16 + n4];
    h[nt] += uid;
  }
  const bool bend = ((t0 + 15) & 4095) == 4095;
  if (bend) {
    float ss = 0.f;
    if (l15 == 15) {
#pragma unroll
      for (int nt = 0; nt < 4; nt++)
#pragma unroll
        for (int j = 0; j < 4; j++) ss += h[nt][j] * h[nt][j];
    }
    ss += __shfl_xor(ss, 16, 64);
    ss += __shfl_xor(ss, 32, 64);
    if (lane == 15) atomicAdd(norm_out, sqrtf(ss) * 0.125f);
  }
#pragma unroll
  for (int nt = 0; nt < 4; nt++) {
    u16x4 pk;
#pragma unroll
    for (int j = 0; j < 4; j++) pk[j] = bf1(h[nt][j]);
    *(u16x4*)&hsT[wid][l15][nt * 16 + n4] = pk;
  }
#pragma unroll
  for (int kk = 0; kk < 2; kk++) {
    bf16x8 hf = ld_frag(&hsT[wid][l15][kk * 32 + q8]);
    *(u16x8*)&hsbF[((size_t)(tt * 2 + kk) * 64 + lane) * 8] =
        __builtin_bit_cast(u16x8, hf);
  }
}

// ---------------------------------------------------------------------------
// G2 weight-stationary: wave pins its d-chunk's CwF frags (8) + Cb in
// registers, streams 4 independent t-tiles: {2 hs-frag loads, 8 MFMA,
// 4 f32x4 stores}. idx = block*4+wid: dc = idx&15, tgroup = idx>>4.
// 2048 blocks x 4 waves = 8192 waves.
// ---------------------------------------------------------------------------
__global__ __launch_bounds__(256, 4) void g2_gemm(const unsigned short* __restrict__ hsbF,
                                                  const unsigned short* __restrict__ CwF,
                                                  const float* __restrict__ Cb,
                                                  const float* __restrict__ Dv,
                                                  const float* __restrict__ x,
                                                  const float* __restrict__ dflag,
                                                  float* __restrict__ out) {
  const int tid = threadIdx.x, lane = tid & 63, wid = tid >> 6;
  const int idx = blockIdx.x * 4 + wid;
  const int dc = idx & 15, tg = idx >> 4;
  const int d0 = dc * 64;
  const int l15 = lane & 15;
  const int n4 = (lane >> 4) * 4;
  const int q8 = (lane >> 4) * 8;
  const bool hasD = (*dflag != 0.0f);
  bf16x8 cw[4][2];
#pragma unroll
  for (int dt = 0; dt < 4; dt++)
#pragma unroll
    for (int kk = 0; kk < 2; kk++)
      cw[dt][kk] = ld_frag(&CwF[(size_t)((((d0 >> 4) + dt) * 2 + kk) * 64 + lane) * 8]);
  f32x4 cb[4], dd[4];
#pragma unroll
  for (int dt = 0; dt < 4; dt++) {
    cb[dt] = *(const f32x4*)&Cb[d0 + dt * 16 + n4];
    dd[dt] = *(const f32x4*)&Dv[d0 + dt * 16 + n4];
  }
#pragma unroll
  for (int s = 0; s < 4; s++) {
    const int tt = tg * 4 + s;
    bf16x8 hf0 = ld_frag(&hsbF[((size_t)(tt * 2 + 0) * 64 + lane) * 8]);
    bf16x8 hf1 = ld_frag(&hsbF[((size_t)(tt * 2 + 1) * 64 + lane) * 8]);
    f32x4 o[4];
#pragma unroll
    for (int dt = 0; dt < 4; dt++) o[dt] = f32x4{0.f, 0.f, 0.f, 0.f};
#pragma unroll
    for (int dt = 0; dt < 4; dt++) {
      o[dt] = mfma16(cw[dt][0], hf0, o[dt]);
      o[dt] = mfma16(cw[dt][1], hf1, o[dt]);
    }
    const int trow = tt * 16 + l15;
    const size_t xrow = (size_t)trow * 1024;
#pragma unroll
    for (int dt = 0; dt < 4; dt++) {
      int db = d0 + dt * 16 + n4;
      f32x4 v = o[dt] + cb[dt];
      if (hasD) {
        f32x4 xv = *(const f32x4*)&x[xrow + db];
        v += dd[dt] * xv;
      }
      *(f32x4*)&out[xrow + db] = v;
    }
  }
}

extern "C" void kernel_launch(void* const* d_in, const int* in_sizes, int n_in,
                              void* d_out, int out_size, void* d_ws, size_t ws_size,
                              hipStream_t stream) {
  const float* x  = (const float*)d_in[0];
  const float* rw = (const float*)d_in[1];
  const float* Al = (const float*)d_in[2];
  const float* Ah = (const float*)d_in[3];
  const float* Bw = (const float*)d_in[4];
  const float* Bb = (const float*)d_in[5];
  const float* Cw = (const float*)d_in[6];
  const float* Cb = (const float*)d_in[7];
  const float* Dv = (const float*)d_in[8];
  float* out = (float*)d_out;

  char* ws = (char*)d_ws;
  unsigned short* akbF  = (unsigned short*)(ws);                      // 32 KiB
  float*          dflag = (float*)(ws + 32768);                       // 4 B
  unsigned short* BwF   = (unsigned short*)(ws + 65536);              // 128 KiB
  unsigned short* CwF   = (unsigned short*)(ws + 196608);             // 128 KiB
  float*          u     = (float*)(ws + 327680);                      // 8 MiB
  unsigned short* hsbF  = (unsigned short*)(ws + 327680 + 8388608);   // 4 MiB

  float* norm_out = out + (out_size - 2);
  float* spec_out = out + (out_size - 1);

  kprep<<<dim3(65), dim3(256), 0, stream>>>(Bw, Cw, Al, Ah, Dv, BwF, CwF, akbF,
                                            dflag, spec_out, norm_out);
  g1_gemm<<<dim3(512), dim3(512), 0, stream>>>(x, BwF, Bb, rw, u);
  k2_hs<<<dim3(512), dim3(256), 0, stream>>>(u, akbF, hsbF, norm_out);
  g2_gemm<<<dim3(2048), dim3(256), 0, stream>>>(hsbF, CwF, Cb, Dv, x, dflag, out);
}